// Round 7
// baseline (189.031 us; speedup 1.0000x reference)
//
#include <hip/hip_runtime.h>

#define BB   128
#define TT   512
#define FF   40
#define WW   10
#define NS   503            // window starts (stride 1): T-W+1
#define NP   780            // F*(F-1)/2
#define SC   32             // steps per block (last chunk overlaps)
#define NCHUNK 16
#define ROWS (SC + WW - 1)  // 41 staged rows
#define XSTR 42             // xst row stride (even; 21 odd -> good bank spread)
#define SSTR 34             // stf row stride in float2 (even; 17 odd -> good spread)
#define EPSC 1e-5f
#define C01  0.31622776601683794f   // sqrt(0.1)

// One block per (b, 32-step s-chunk), 8 blocks/CU (100% occupancy).
// TRANSPOSED LDS: xst[f][t], stf[f][t]=(u*sqrt(0.1), m*u) so the 2-step body
// reads are guaranteed-wide: per pair-slot per 2 steps:
//   1x b64 (x_i @ t+10,t+11) + 1x b64 (x_j) + 1x b128 (stat_i) + 1x b128 (stat_j)
// Stores remain fully coalesced dwords at p = tid + k*256.
__global__ __launch_bounds__(256, 8) void ts_corr_r7(const float* __restrict__ in,
                                                     float* __restrict__ out) {
    const int blk = blockIdx.x;
    const int b   = blk >> 4;              // / NCHUNK
    const int c   = blk & (NCHUNK - 1);
    const int s0  = (c == NCHUNK - 1) ? (NS - SC) : c * SC;   // 471 tail; overlap writes identical
    const int tid = threadIdx.x;

    __shared__ __align__(16) float  xst[FF][XSTR];   // 6720 B
    __shared__ __align__(16) float2 stf[FF][SSTR];   // 10880 B

    // ---- phase 0: stage slab (coalesced float4 global reads) -> transposed LDS ----
    const float4* src4 = (const float4*)(in + ((size_t)b * TT + s0) * FF);
    #pragma unroll
    for (int k = 0; k < 2; ++k) {
        const int q = tid + k * 256;
        if (q < ROWS * FF / 4) {           // 410 quads
            const int r  = q / 10;
            const int f0 = (q - r * 10) * 4;
            const float4 v = src4[q];
            xst[f0    ][r] = v.x;
            xst[f0 + 1][r] = v.y;
            xst[f0 + 2][r] = v.z;
            xst[f0 + 3][r] = v.w;
        }
    }
    __syncthreads();

    // ---- phase 1a (threads 0..159): rolling stats, f = tid>>2, 8 t's each ----
    if (tid < 160) {
        const int f  = tid >> 2;
        const int t0 = (tid & 3) * 8;
        float sx = 0.f, sxx = 0.f;
        #pragma unroll
        for (int w = 0; w < WW; ++w) {
            const float x = xst[f][t0 + w];
            sx += x; sxx += x * x;
        }
        #pragma unroll
        for (int u = 0; u < 8; ++u) {
            const int t = t0 + u;
            const float m  = sx * 0.1f;
            const float vv = fmaxf(sxx * 0.1f - m * m, 0.f);
            const float iu = 1.f / (sqrtf(vv) + EPSC);
            stf[f][t] = make_float2(iu * C01, m * iu);
            if (u < 7) {
                const float xo = xst[f][t], xn = xst[f][t + WW];
                sx  += xn - xo;
                sxx += xn * xn - xo * xo;
            }
        }
    }

    // ---- phase 1b (all threads): pair setup + initial window from xst ----
    int pi[4], pj[4];
    float sxy[4], ph[4][WW];
    #pragma unroll
    for (int k = 0; k < 4; ++k) {
        const int p = tid + k * 256;
        const int pp = (p < NP) ? p : 0;
        int i = (int)((79.0f - sqrtf((float)(6241 - 8 * pp))) * 0.5f);
        while (i > 0 && i * (79 - i) / 2 > pp) --i;
        while ((i + 1) * (79 - (i + 1)) / 2 <= pp) ++i;
        pi[k] = i;
        pj[k] = pp - i * (79 - i) / 2 + i + 1;
        float s = 0.f;
        #pragma unroll
        for (int w2 = 0; w2 < WW; w2 += 2) {
            const float2 xi = *(const float2*)&xst[pi[k]][w2];
            const float2 xj = *(const float2*)&xst[pj[k]][w2];
            const float p0 = xi.x * xj.x, p1 = xi.y * xj.y;
            ph[k][w2]     = p0;
            ph[k][w2 + 1] = p1;
            s += p0 + p1;
        }
        sxy[k] = s;
    }
    __syncthreads();   // stf ready; no barriers after this

    float* dst0 = out + (size_t)(b * NS + s0) * NP + tid;

// Two steps (TA, TA+1) per expansion; U is a literal (static ph index).
// All reads guaranteed-wide on the transposed layouts (TA always even).
#define STEP2(U, TA, DO2) do {                                                  \
    const int _tA = (TA);                                                       \
    float* _dA = dst0 + (size_t)_tA * NP;                                       \
    float* _dB = _dA + NP;                                                      \
    _Pragma("unroll")                                                           \
    for (int k = 0; k < 3; ++k) {                                               \
        const float2 _xi = *(const float2*)&xst[pi[k]][_tA + WW];               \
        const float2 _xj = *(const float2*)&xst[pj[k]][_tA + WW];               \
        const float4 _si = *(const float4*)&stf[pi[k]][_tA];                    \
        const float4 _sj = *(const float4*)&stf[pj[k]][_tA];                    \
        _dA[k * 256] = sxy[k] * _si.x * _sj.x - _si.y * _sj.y;                  \
        const float _pn = _xi.x * _xj.x;                                        \
        sxy[k] += _pn - ph[k][U]; ph[k][U] = _pn;                               \
        _dB[k * 256] = sxy[k] * _si.z * _sj.z - _si.w * _sj.w;                  \
        if (DO2) {                                                              \
            const float _p2 = _xi.y * _xj.y;                                    \
            sxy[k] += _p2 - ph[k][(U) + 1]; ph[k][(U) + 1] = _p2;               \
        }                                                                       \
    }                                                                           \
    if (tid < 12) {                                                             \
        const float2 _xi = *(const float2*)&xst[pi[3]][_tA + WW];               \
        const float2 _xj = *(const float2*)&xst[pj[3]][_tA + WW];               \
        const float4 _si = *(const float4*)&stf[pi[3]][_tA];                    \
        const float4 _sj = *(const float4*)&stf[pj[3]][_tA];                    \
        _dA[768] = sxy[3] * _si.x * _sj.x - _si.y * _sj.y;                      \
        const float _pn = _xi.x * _xj.x;                                        \
        sxy[3] += _pn - ph[3][U]; ph[3][U] = _pn;                               \
        _dB[768] = sxy[3] * _si.z * _sj.z - _si.w * _sj.w;                      \
        if (DO2) {                                                              \
            const float _p2 = _xi.y * _xj.y;                                    \
            sxy[3] += _p2 - ph[3][(U) + 1]; ph[3][(U) + 1] = _p2;               \
        }                                                                       \
    }                                                                           \
} while (0)

    // ---- phase 2: t = 0..29 regular, epilogue t = 30..31 ----
    for (int t0 = 0; t0 < 30; t0 += WW) {
        STEP2(0, t0,     true);
        STEP2(2, t0 + 2, true);
        STEP2(4, t0 + 4, true);
        STEP2(6, t0 + 6, true);
        STEP2(8, t0 + 8, true);
    }
    STEP2(0, 30, false);   // xi.y/xj.y read pad col 41 but are unused (DO2=false)
#undef STEP2
}

extern "C" void kernel_launch(void* const* d_in, const int* in_sizes, int n_in,
                              void* d_out, int out_size, void* d_ws, size_t ws_size,
                              hipStream_t stream) {
    const float* in = (const float*)d_in[0];
    float* out = (float*)d_out;
    ts_corr_r7<<<BB * NCHUNK, 256, 0, stream>>>(in, out);
}

// Round 8
// 45.823 us; speedup vs baseline: 4.1252x; 4.1252x over previous
//
#include <hip/hip_runtime.h>

#define BB   128
#define TT   512
#define FF   40
#define WW   10
#define NS   503            // window starts (stride 1): T-W+1
#define NP   780            // F*(F-1)/2
#define SC   64             // steps per block (uniform; last chunk overlaps)
#define NCHUNK 8
#define ROWS (SC + WW - 1)  // 73 staged rows
#define NT   512            // threads per block (8 waves)
#define EPSC 1e-5f
#define C01  0.31622776601683794f   // sqrt(0.1)

// 512 threads x 2 pair-slots (ph[2][10] = 20 regs -> fits 64-VGPR cap).
// Grid 1024 blocks x 8 waves = 8192 waves = exactly 32 waves/CU (one generation).
// Slot0: p = tid (always active). Slot1: p = tid + 512 (active iff tid < 268).
// 2-step fused body: paired LDS reads (delta 40 dwords / 40 qwords) merge into
// ds_read2_b32 / ds_read2_b64. Stores fully coalesced dwords.
__global__ __launch_bounds__(NT, 8) void ts_corr_r8(const float* __restrict__ in,
                                                    float* __restrict__ out) {
    const int blk = blockIdx.x;
    const int b   = blk >> 3;              // / NCHUNK
    const int c   = blk & (NCHUNK - 1);
    const int s0  = (c == NCHUNK - 1) ? (NS - SC) : c * SC;   // 439 tail; overlap rows identical
    const int tid = threadIdx.x;

    __shared__ float  xs[SC + WW][FF];   // 74 rows (73 used + pad) = 11840 B
    __shared__ float2 st[SC][FF];        // (u*sqrt(0.1), m*u) = 20480 B

    // ---- phase 0: stage 73-row slab, float4 (730 quads) ----
    const float4* src4 = (const float4*)(in + ((size_t)b * TT + s0) * FF);
    float4* xs4 = (float4*)&xs[0][0];
    {
        xs4[tid] = src4[tid];                       // 0..511
        const int i2 = tid + NT;
        if (i2 < ROWS * FF / 4) xs4[i2] = src4[i2]; // 512..729
    }
    __syncthreads();

    // ---- phase 1: stats for all 64 steps (640 feature-quads) ----
    #pragma unroll
    for (int k = 0; k < 2; ++k) {
        const int qd = tid + k * NT;
        if (qd < SC * FF / 4) {
            const int t  = qd / 10;
            const int f0 = (qd - t * 10) * 4;
            float sx0=0,sx1=0,sx2=0,sx3=0, sq0=0,sq1=0,sq2=0,sq3=0;
            #pragma unroll
            for (int w = 0; w < WW; ++w) {
                const float4 x = *(const float4*)&xs[t + w][f0];
                sx0 += x.x; sx1 += x.y; sx2 += x.z; sx3 += x.w;
                sq0 += x.x*x.x; sq1 += x.y*x.y; sq2 += x.z*x.z; sq3 += x.w*x.w;
            }
            const float m0 = sx0*0.1f, m1 = sx1*0.1f, m2 = sx2*0.1f, m3 = sx3*0.1f;
            const float u0 = 1.f/(sqrtf(fmaxf(sq0*0.1f - m0*m0, 0.f)) + EPSC);
            const float u1 = 1.f/(sqrtf(fmaxf(sq1*0.1f - m1*m1, 0.f)) + EPSC);
            const float u2 = 1.f/(sqrtf(fmaxf(sq2*0.1f - m2*m2, 0.f)) + EPSC);
            const float u3 = 1.f/(sqrtf(fmaxf(sq3*0.1f - m3*m3, 0.f)) + EPSC);
            *(float4*)&st[t][f0]     = make_float4(u0*C01, m0*u0, u1*C01, m1*u1);
            *(float4*)&st[t][f0 + 2] = make_float4(u2*C01, m2*u2, u3*C01, m3*u3);
        }
    }

    // ---- pair setup + initial window (xs ready since phase-0 barrier) ----
    int pi[2], pj[2];
    float sxy[2], ph[2][WW];
    #pragma unroll
    for (int k = 0; k < 2; ++k) {
        const int p = tid + k * NT;
        const int pp = (p < NP) ? p : 0;
        int i = (int)((79.0f - sqrtf((float)(6241 - 8 * pp))) * 0.5f);
        while (i > 0 && i * (79 - i) / 2 > pp) --i;
        while ((i + 1) * (79 - (i + 1)) / 2 <= pp) ++i;
        pi[k] = i;
        pj[k] = pp - i * (79 - i) / 2 + i + 1;
        float s = 0.f;
        #pragma unroll
        for (int w = 0; w < WW; ++w) {
            const float pr = xs[w][pi[k]] * xs[w][pj[k]];
            ph[k][w] = pr;
            s += pr;
        }
        sxy[k] = s;
    }
    __syncthreads();   // st ready; no barriers after this

    const bool act1 = (tid < NP - NT);   // slot-1 live lanes (tid < 268)
    float* dst0 = out + (size_t)(b * NS + s0) * NP + tid;

// Two steps (TA, TA+1); U is a literal (static ph index); DO2 literal.
#define SLOT(K, OFF) do {                                                       \
    const int _ii = pi[K], _jj = pj[K];                                         \
    const float  _xiA = xs[_tA + WW][_ii], _xiB = xs[_tA + WW + 1][_ii];        \
    const float  _xjA = xs[_tA + WW][_jj], _xjB = xs[_tA + WW + 1][_jj];        \
    const float2 _siA = st[_tA][_ii],      _siB = st[_tA + 1][_ii];             \
    const float2 _sjA = st[_tA][_jj],      _sjB = st[_tA + 1][_jj];             \
    _dA[OFF] = sxy[K] * _siA.x * _sjA.x - _siA.y * _sjA.y;                      \
    const float _pn = _xiA * _xjA;                                              \
    sxy[K] += _pn - ph[K][U]; ph[K][U] = _pn;                                   \
    _dB[OFF] = sxy[K] * _siB.x * _sjB.x - _siB.y * _sjB.y;                      \
    if (DO2) {                                                                  \
        const float _p2 = _xiB * _xjB;                                          \
        sxy[K] += _p2 - ph[K][(U) + 1]; ph[K][(U) + 1] = _p2;                   \
    }                                                                           \
} while (0)

#define STEP2(UU, TA, DD) do {                                                  \
    const int _tA = (TA);                                                       \
    const int U = (UU);                                                         \
    const bool DO2 = (DD);                                                      \
    float* _dA = dst0 + (size_t)_tA * NP;                                       \
    float* _dB = _dA + NP;                                                      \
    SLOT(0, 0);                                                                 \
    if (act1) SLOT(1, NT);                                                      \
} while (0)

    // ---- phase 2: t = 0..59 regular, epilogue t = 60..63 ----
    for (int t0 = 0; t0 < 60; t0 += WW) {
        STEP2(0, t0,     true);
        STEP2(2, t0 + 2, true);
        STEP2(4, t0 + 4, true);
        STEP2(6, t0 + 6, true);
        STEP2(8, t0 + 8, true);
    }
    STEP2(0, 60, true);
    STEP2(2, 62, false);
#undef STEP2
#undef SLOT
}

extern "C" void kernel_launch(void* const* d_in, const int* in_sizes, int n_in,
                              void* d_out, int out_size, void* d_ws, size_t ws_size,
                              hipStream_t stream) {
    const float* in = (const float*)d_in[0];
    float* out = (float*)d_out;
    ts_corr_r8<<<BB * NCHUNK, NT, 0, stream>>>(in, out);
}